// Round 6
// baseline (207.697 us; speedup 1.0000x reference)
//
#include <hip/hip_runtime.h>
#include <hip/hip_bf16.h>

#define NB 128
#define NT 1024
#define ND 512
#define NDA 576   // 512 (memory) + 64 (im2col window, 62 used + 2 zero pad)
#define NQ 1024
#define NA 128
#define NF 32
#define NK 31
#define CT 32
#define NCHUNK (NT / CT)   // 32
#define ROWB 1152          // bytes per LDS row (576 bf16)

typedef __attribute__((ext_vector_type(8))) short short8;
typedef __attribute__((ext_vector_type(4))) float f32x4;
typedef __attribute__((ext_vector_type(4))) unsigned int u32x4;

__device__ __forceinline__ unsigned short f2bf(float f) {
  unsigned int u = __float_as_uint(f);
  u += 0x7fffu + ((u >> 16) & 1u);   // RNE; inputs are finite
  return (unsigned short)(u >> 16);
}
__device__ __forceinline__ unsigned int cvt_pk_bf16(float lo, float hi) {
  unsigned int r;
  asm("v_cvt_pk_bf16_f32 %0, %1, %2" : "=v"(r) : "v"(lo), "v"(hi));
  return r;
}
__device__ __forceinline__ float bf2f(unsigned short u) {
  return __uint_as_float((unsigned int)u << 16);
}
__device__ __forceinline__ float fast_tanh(float x) {
  const float e = __expf(2.f * x);
  return 1.f - 2.f / (e + 1.f);
}

// ---------------------------------------------------------------------------
// Prep: identical to R5 (pq partials, Wt bf16 transpose, W2 = ck@Wloc).
// ---------------------------------------------------------------------------
__global__ __launch_bounds__(256) void lsa_prep(
    const float* __restrict__ query, const float* __restrict__ wq,
    const float* __restrict__ wm, const float* __restrict__ ck,
    const float* __restrict__ wloc,
    float* __restrict__ pq_part, unsigned short* __restrict__ wt_g)
{
  const int bid = blockIdx.x;
  const int tid = threadIdx.x;
  if (bid < 512) {
    __shared__ float qs[256];
    __shared__ float red[256];
    const int b = bid >> 2;
    const int qg = bid & 3;
    qs[tid] = query[(size_t)b * NQ + qg * 256 + tid];
    __syncthreads();
    const int a = tid & 127;
    const int h = tid >> 7;
    const float* wqp = wq + (size_t)(qg * 256 + h * 128) * NA + a;
    float acc = 0.f;
#pragma unroll 8
    for (int qi = 0; qi < 128; ++qi)
      acc += qs[h * 128 + qi] * wqp[(size_t)qi * NA];
    red[tid] = acc;
    __syncthreads();
    if (h == 0) pq_part[((size_t)b * 4 + qg) * NA + a] = red[a] + red[128 + a];
  } else if (bid < 576) {
    const int blk = bid - 512;
    for (int i = blk * 1024 + tid; i < blk * 1024 + 1024; i += 256) {
      const int dd = i >> 7, aa = i & 127;
      wt_g[(size_t)aa * NDA + dd] = f2bf(wm[(size_t)dd * NA + aa]);
    }
  } else {
    __shared__ float wl_s[NF * NA];
    __shared__ float ck_s[NK * 2 * NF];
    const int blk = bid - 576;
    for (int i = tid; i < NF * NA; i += 256) wl_s[i] = wloc[i];
    for (int i = tid; i < NK * 2 * NF; i += 256) ck_s[i] = ck[i];
    __syncthreads();
    const int a = tid & 127;
    const int h = tid >> 7;
#pragma unroll
    for (int wi = 0; wi < 4; ++wi) {
      const int w = blk * 8 + h * 4 + wi;
      float acc = 0.f;
      if (w < 62) {
        const int k = w >> 1, ch = w & 1;
#pragma unroll
        for (int f = 0; f < NF; ++f)
          acc += ck_s[k * 64 + ch * 32 + f] * wl_s[f * NA + a];
      }
      wt_g[(size_t)a * NDA + 512 + w] = f2bf(acc);
    }
  }
}

// ---------------------------------------------------------------------------
// Main: persistent (b, quarter) blocks. Waves 0-3: GEMM+softmax+context.
// Waves 4-7: 2-chunks-ahead register-staged pipeline into dbuf LDS.
// ---------------------------------------------------------------------------

// staging: load 64 floats (one row, slot-block su) as 16 named f32x4
#define VLOAD(t0n_) { \
  const float* src_ = memory + ((size_t)b * NT + (t0n_) + sr) * ND + su * 64; \
  S0  = *(const f32x4*)(src_ +  0); S1  = *(const f32x4*)(src_ +  4); \
  S2  = *(const f32x4*)(src_ +  8); S3  = *(const f32x4*)(src_ + 12); \
  S4  = *(const f32x4*)(src_ + 16); S5  = *(const f32x4*)(src_ + 20); \
  S6  = *(const f32x4*)(src_ + 24); S7  = *(const f32x4*)(src_ + 28); \
  S8  = *(const f32x4*)(src_ + 32); S9  = *(const f32x4*)(src_ + 36); \
  S10 = *(const f32x4*)(src_ + 40); S11 = *(const f32x4*)(src_ + 44); \
  S12 = *(const f32x4*)(src_ + 48); S13 = *(const f32x4*)(src_ + 52); \
  S14 = *(const f32x4*)(src_ + 56); S15 = *(const f32x4*)(src_ + 60); }

#define VW1(sa_, sb_, s_) { u32x4 k_; \
  k_[0] = cvt_pk_bf16(sa_[0], sa_[1]); k_[1] = cvt_pk_bf16(sa_[2], sa_[3]); \
  k_[2] = cvt_pk_bf16(sb_[0], sb_[1]); k_[3] = cvt_pk_bf16(sb_[2], sb_[3]); \
  *(u32x4*)(dr_ + ((su * 128 + (s_) * 16) ^ ssw)) = k_; }

#define VWRITE(buf_) { char* dr_ = (char*)(buf_) + sr * ROWB; \
  VW1(S0,S1,0) VW1(S2,S3,1) VW1(S4,S5,2) VW1(S6,S7,3) \
  VW1(S8,S9,4) VW1(S10,S11,5) VW1(S12,S13,6) VW1(S14,S15,7) }

#define IML(i_) { const int w_ = w0i + i_; float v_ = 0.f; \
  if (w_ < 62) { const int t3_ = (t0n_) - 15 + (w_ >> 1) + tIi; \
    if (t3_ >= 0 && t3_ < NT) \
      v_ = (w_ & 1) ? cum[(size_t)b * NT + t3_] : prev[(size_t)b * NT + t3_]; } \
  iw##i_ = v_; }

#define IMLOAD(t0n_arg) { const int t0n_ = (t0n_arg); \
  IML(0) IML(1) IML(2) IML(3) IML(4) IML(5) IML(6) IML(7) }

#define IMWRITE(buf_) { u32x4 k_; \
  k_[0] = cvt_pk_bf16(iw0, iw1); k_[1] = cvt_pk_bf16(iw2, iw3); \
  k_[2] = cvt_pk_bf16(iw4, iw5); k_[3] = cvt_pk_bf16(iw6, iw7); \
  *(u32x4*)((char*)(buf_) + tIi * ROWB + ((1024 + w0i * 2) ^ ((tIi & 7) << 4))) = k_; }

__global__ __launch_bounds__(512, 4) void lsa_main(
    const float* __restrict__ memory, const int* __restrict__ msl,
    const float* __restrict__ prev, const float* __restrict__ cum,
    const float* __restrict__ pq_part, const float* __restrict__ v_g,
    const unsigned short* __restrict__ wt_g,
    float* __restrict__ score_g, float* __restrict__ pm_g,
    float* __restrict__ pl_g, float* __restrict__ pctx_g)
{
  const int bid = blockIdx.x;
  const int b = bid >> 2;
  const int q = bid & 3;
  const int len = msl[b];
  const int ncv = (len + 31) >> 5;
  const int nk = (ncv > q) ? ((ncv - q + 3) >> 2) : 0;
  if (nk <= 0) return;
  const int tid = threadIdx.x;
  const int wid = tid >> 6;
  const int lane = tid & 63;

  __shared__ __align__(16) unsigned short sv[2][CT * NDA];  // 2 x 36 KB
  __shared__ float pq_s[NA];
  __shared__ float v_s[NA];
  __shared__ float score2[4][CT];

  // staging identity (waves 4-7)
  const int it2 = tid - 256;          // 0..255 on staging waves
  const int sr = it2 >> 3;            // row 0..31
  const int su = it2 & 7;             // 128-B slot block
  const int ssw = (sr & 7) << 4;
  const int tIi = it2 >> 3;           // im2col row
  const int w0i = (it2 & 7) * 8;      // im2col w-base (8 w's)

  f32x4 S0, S1, S2, S3, S4, S5, S6, S7, S8, S9, S10, S11, S12, S13, S14, S15;
  float iw0, iw1, iw2, iw3, iw4, iw5, iw6, iw7;

  // ---------------- prologue ----------------
  if (wid >= 4) {
    if (it2 < NA) {
      const float* pp = pq_part + (size_t)b * 4 * NA + it2;
      pq_s[it2] = pp[0] + pp[NA] + pp[2 * NA] + pp[3 * NA];
      v_s[it2] = v_g[it2];
    }
    VLOAD(q * CT); IMLOAD(q * CT);
    VWRITE(sv[0]); IMWRITE(sv[0]);
    if (nk > 1) { VLOAD((q + 4) * CT); IMLOAD((q + 4) * CT); }
  }
  __syncthreads();

  const int llo = lane & 15, lhi = lane >> 4;

  // ---------------- chunk loop ----------------
  for (int j = 0; j < nk; ++j) {
    const int ci = q + 4 * j;
    const int t0 = ci * CT;
    const int p = j & 1;
    const int cid = b * NCHUNK + ci;
    const int nvalid = min(CT, len - t0);
    float esc = 0.f;

    if (wid < 4) {
      // ---- GEMM: 32(t) x 32 cols (2 col-tiles) x 576(k) ----
      const unsigned short* bp0 = wt_g + (size_t)(wid * 32 + llo) * NDA + lhi * 8;
      const unsigned short* bp1 = bp0 + (size_t)16 * NDA;
      const char* a0b = (const char*)sv[p] + llo * ROWB;
      const char* a1b = (const char*)sv[p] + (16 + llo) * ROWB;
      f32x4 acc00 = {0.f, 0.f, 0.f, 0.f};
      f32x4 acc01 = {0.f, 0.f, 0.f, 0.f};
      f32x4 acc10 = {0.f, 0.f, 0.f, 0.f};
      f32x4 acc11 = {0.f, 0.f, 0.f, 0.f};
#pragma unroll
      for (int kf = 0; kf < 18; ++kf) {
        const short8 b0 = *(const short8*)(bp0 + kf * 32);
        const short8 b1 = *(const short8*)(bp1 + kf * 32);
        const int bo = (kf * 64 + lhi * 16) ^ ((llo & 7) << 4);
        const short8 a0 = *(const short8*)(a0b + bo);
        const short8 a1 = *(const short8*)(a1b + bo);
        acc00 = __builtin_amdgcn_mfma_f32_16x16x32_bf16(a0, b0, acc00, 0, 0, 0);
        acc10 = __builtin_amdgcn_mfma_f32_16x16x32_bf16(a1, b0, acc10, 0, 0, 0);
        acc01 = __builtin_amdgcn_mfma_f32_16x16x32_bf16(a0, b1, acc01, 0, 0, 0);
        acc11 = __builtin_amdgcn_mfma_f32_16x16x32_bf16(a1, b1, acc11, 0, 0, 0);
      }
      const float pq0 = pq_s[wid * 32 + llo],      vc0 = v_s[wid * 32 + llo];
      const float pq1 = pq_s[wid * 32 + 16 + llo], vc1 = v_s[wid * 32 + 16 + llo];
#pragma unroll
      for (int rt = 0; rt < 2; ++rt) {
        const f32x4 aa = rt ? acc10 : acc00;
        const f32x4 ab = rt ? acc11 : acc01;
#pragma unroll
        for (int rg = 0; rg < 4; ++rg) {
          float e = fast_tanh(aa[rg] + pq0) * vc0 + fast_tanh(ab[rg] + pq1) * vc1;
          e += __shfl_xor(e, 1); e += __shfl_xor(e, 2);
          e += __shfl_xor(e, 4); e += __shfl_xor(e, 8);
          if (llo == 0) score2[wid][rt * 16 + lhi * 4 + rg] = e;
        }
      }
    } else {
      // ---- staging waves: write chunk j+1 (loaded last iter), load j+2 ----
      if (j + 1 < nk) { VWRITE(sv[1 - p]); IMWRITE(sv[1 - p]); }
      if (j + 2 < nk) { VLOAD((q + 4 * (j + 2)) * CT); IMLOAD((q + 4 * (j + 2)) * CT); }
    }
    __syncthreads();   // bar1: score2 ready; sv[1-p] fully staged

    if (wid < 4) {
      // ---- softmax (4-wave redundant) ----
      const int t = lane & 31;
      const float s = score2[0][t] + score2[1][t] + score2[2][t] + score2[3][t];
      if (wid == 0 && lane < CT) score_g[(size_t)b * NT + t0 + t] = s;
      float sm = (t < nvalid) ? s : -3.4e38f;
      sm = fmaxf(sm, __shfl_xor(sm, 1));  sm = fmaxf(sm, __shfl_xor(sm, 2));
      sm = fmaxf(sm, __shfl_xor(sm, 4));  sm = fmaxf(sm, __shfl_xor(sm, 8));
      sm = fmaxf(sm, __shfl_xor(sm, 16));
      esc = (t < nvalid) ? __expf(s - sm) : 0.f;
      float l = esc;
      l += __shfl_xor(l, 1);  l += __shfl_xor(l, 2);  l += __shfl_xor(l, 4);
      l += __shfl_xor(l, 8);  l += __shfl_xor(l, 16);
      if (wid == 0 && lane == 0) { pm_g[cid] = sm; pl_g[cid] = l; }

      // ---- context: 4 waves x 16 d-groups, lanes split t 4-ways ----
      const int gi = lane >> 2;
      const int g = wid * 16 + gi;         // d-group, d0 = 8g
      const int sub = lane & 3;
      const char* svb = (const char*)sv[p];
      float a8[8];
#pragma unroll
      for (int i = 0; i < 8; ++i) a8[i] = 0.f;
#pragma unroll
      for (int tp = 0; tp < 8; ++tp) {
        const int t2 = tp * 4 + sub;
        const float ee = __shfl(esc, t2);
        const short8 u = *(const short8*)(svb + t2 * ROWB + 16 * (g ^ (t2 & 7)));
#pragma unroll
        for (int i = 0; i < 8; ++i) a8[i] += ee * bf2f((unsigned short)u[i]);
      }
#pragma unroll
      for (int i = 0; i < 8; ++i) {
        a8[i] += __shfl_xor(a8[i], 1);
        a8[i] += __shfl_xor(a8[i], 2);
      }
      if (sub == 0) {
        float* dst = pctx_g + (size_t)cid * ND + g * 8;
        const f32x4 lo = {a8[0], a8[1], a8[2], a8[3]};
        const f32x4 hi = {a8[4], a8[5], a8[6], a8[7]};
        *(f32x4*)dst = lo;
        *(f32x4*)(dst + 4) = hi;
      }
    }
    __syncthreads();   // bar2: context-j reads done; buffers rotate
  }
}

// ---------------------------------------------------------------------------
// Combine: merge chunk partials; write context, attn, new_cum. Grid NB*2.
// ---------------------------------------------------------------------------
__global__ __launch_bounds__(256) void lsa_comb(
    const int* __restrict__ msl, const float* __restrict__ score_g,
    const float* __restrict__ cum, const float* __restrict__ pm_g,
    const float* __restrict__ pl_g, const float* __restrict__ pctx_g,
    float* __restrict__ out)
{
  const int bid = blockIdx.x;
  const int b = bid >> 1;
  const int hf = bid & 1;
  const int tid = threadIdx.x;
  const int len = msl[b];
  const int nck = (len + CT - 1) / CT;
  __shared__ float coef[NCHUNK];
  __shared__ float MLsh[2];
  if (tid < 64) {
    const int i = tid;
    const float m = (i < nck) ? pm_g[b * NCHUNK + i] : -3.4e38f;
    const float l = (i < nck) ? pl_g[b * NCHUNK + i] : 0.f;
    float M = m;
#pragma unroll
    for (int off = 1; off < 64; off <<= 1) M = fmaxf(M, __shfl_xor(M, off));
    const float c = __expf(m - M);
    float L = l * c;
#pragma unroll
    for (int off = 1; off < 64; off <<= 1) L += __shfl_xor(L, off);
    if (i < NCHUNK) coef[i] = c;
    if (i == 0) { MLsh[0] = M; MLsh[1] = L; }
  }
  __syncthreads();
  const float M = MLsh[0];
  const float Linv = 1.f / MLsh[1];
  {
    const int d = hf * 256 + tid;
    float acc = 0.f;
    for (int i = 0; i < nck; ++i)
      acc += pctx_g[((size_t)b * NCHUNK + i) * ND + d] * coef[i];
    out[(size_t)b * ND + d] = acc * Linv;
  }
  float* attn_o = out + (size_t)NB * ND;
  float* cum_o = attn_o + (size_t)NB * NT;
#pragma unroll
  for (int it = 0; it < 2; ++it) {
    const int t = hf * 512 + it * 256 + tid;
    float w = 0.f;
    if (t < len) w = __expf(score_g[(size_t)b * NT + t] - M) * Linv;
    attn_o[(size_t)b * NT + t] = w;
    cum_o[(size_t)b * NT + t] = w + cum[(size_t)b * NT + t];
  }
}

extern "C" void kernel_launch(void* const* d_in, const int* in_sizes, int n_in,
                              void* d_out, int out_size, void* d_ws, size_t ws_size,
                              hipStream_t stream) {
  const float* query  = (const float*)d_in[0];
  const float* prev   = (const float*)d_in[1];
  const float* cum    = (const float*)d_in[2];
  const float* memory = (const float*)d_in[3];
  const int*   msl    = (const int*)d_in[4];
  const float* wq     = (const float*)d_in[5];
  const float* wm     = (const float*)d_in[6];
  const float* ck     = (const float*)d_in[7];
  const float* wloc   = (const float*)d_in[8];
  const float* vv     = (const float*)d_in[9];
  float* out = (float*)d_out;

  float* ws = (float*)d_ws;
  float* score_g = ws;                        // 131072
  float* pm_g    = ws + 131072;               // 4096
  float* pl_g    = ws + 135168;               // 4096
  float* pctx_g  = ws + 139264;               // 2097152
  float* pq_part = ws + 2236416;              // 65536
  unsigned short* wt_g = (unsigned short*)(ws + 2301952);  // 128*576 bf16

  lsa_prep<<<584, 256, 0, stream>>>(query, wq, wm, ck, wloc, pq_part, wt_g);
  lsa_main<<<NB * 4, 512, 0, stream>>>(memory, msl, prev, cum, pq_part, vv,
                                       wt_g, score_g, pm_g, pl_g, pctx_g);
  lsa_comb<<<NB * 2, 256, 0, stream>>>(msl, score_g, cum, pm_g, pl_g, pctx_g, out);
}

// Round 7
// 112.507 us; speedup vs baseline: 1.8461x; 1.8461x over previous
//
#include <hip/hip_runtime.h>
#include <hip/hip_bf16.h>

#define NB 128
#define NT 1024
#define ND 512
#define NDA 576   // 512 (memory) + 64 (im2col window, 62 used + 2 zero pad)
#define NQ 1024
#define NA 128
#define NF 32
#define NK 31
#define CT 32
#define NCHUNK (NT / CT)   // 32
#define ROWB 1152          // bytes per LDS sv row (576 bf16)

typedef __attribute__((ext_vector_type(8))) short short8;
typedef __attribute__((ext_vector_type(4))) float f32x4;
typedef __attribute__((ext_vector_type(4))) unsigned int u32x4;

__device__ __forceinline__ unsigned short f2bf(float f) {
  unsigned int u = __float_as_uint(f);
  u += 0x7fffu + ((u >> 16) & 1u);   // RNE; inputs are finite
  return (unsigned short)(u >> 16);
}
__device__ __forceinline__ unsigned int cvt_pk_bf16(float lo, float hi) {
  unsigned int r;
  asm("v_cvt_pk_bf16_f32 %0, %1, %2" : "=v"(r) : "v"(lo), "v"(hi));
  return r;
}
__device__ __forceinline__ float bf2f(unsigned short u) {
  return __uint_as_float((unsigned int)u << 16);
}
__device__ __forceinline__ float fast_tanh(float x) {
  const float e = __expf(2.f * x);
  return 1.f - 2.f / (e + 1.f);
}
// async HBM -> LDS, 16B per lane (1 KB per wave per issue)
__device__ __forceinline__ void dma16(const float* g, float* l) {
  __builtin_amdgcn_global_load_lds((const unsigned int*)g, (unsigned int*)l,
                                   16, 0, 0);
}

// ---------------------------------------------------------------------------
// Prep: identical to R5 (pq partials, Wt bf16 transpose, W2 = ck@Wloc).
// ---------------------------------------------------------------------------
__global__ __launch_bounds__(256) void lsa_prep(
    const float* __restrict__ query, const float* __restrict__ wq,
    const float* __restrict__ wm, const float* __restrict__ ck,
    const float* __restrict__ wloc,
    float* __restrict__ pq_part, unsigned short* __restrict__ wt_g)
{
  const int bid = blockIdx.x;
  const int tid = threadIdx.x;
  if (bid < 512) {
    __shared__ float qs[256];
    __shared__ float red[256];
    const int b = bid >> 2;
    const int qg = bid & 3;
    qs[tid] = query[(size_t)b * NQ + qg * 256 + tid];
    __syncthreads();
    const int a = tid & 127;
    const int h = tid >> 7;
    const float* wqp = wq + (size_t)(qg * 256 + h * 128) * NA + a;
    float acc = 0.f;
#pragma unroll 8
    for (int qi = 0; qi < 128; ++qi)
      acc += qs[h * 128 + qi] * wqp[(size_t)qi * NA];
    red[tid] = acc;
    __syncthreads();
    if (h == 0) pq_part[((size_t)b * 4 + qg) * NA + a] = red[a] + red[128 + a];
  } else if (bid < 576) {
    const int blk = bid - 512;
    for (int i = blk * 1024 + tid; i < blk * 1024 + 1024; i += 256) {
      const int dd = i >> 7, aa = i & 127;
      wt_g[(size_t)aa * NDA + dd] = f2bf(wm[(size_t)dd * NA + aa]);
    }
  } else {
    __shared__ float wl_s[NF * NA];
    __shared__ float ck_s[NK * 2 * NF];
    const int blk = bid - 576;
    for (int i = tid; i < NF * NA; i += 256) wl_s[i] = wloc[i];
    for (int i = tid; i < NK * 2 * NF; i += 256) ck_s[i] = ck[i];
    __syncthreads();
    const int a = tid & 127;
    const int h = tid >> 7;
#pragma unroll
    for (int wi = 0; wi < 4; ++wi) {
      const int w = blk * 8 + h * 4 + wi;
      float acc = 0.f;
      if (w < 62) {
        const int k = w >> 1, ch = w & 1;
#pragma unroll
        for (int f = 0; f < NF; ++f)
          acc += ck_s[k * 64 + ch * 32 + f] * wl_s[f * NA + a];
      }
      wt_g[(size_t)a * NDA + 512 + w] = f2bf(acc);
    }
  }
}

// ---------------------------------------------------------------------------
// Main: persistent (b, par) blocks, chunks ci = par + 4j. Async global->LDS
// DMA of the f32 chunk (no staging registers/waves); per-wave convert of
// the rows it DMA'd; B in registers; 3 barriers per chunk.
// ---------------------------------------------------------------------------
__global__ __launch_bounds__(512, 2) void lsa_main(
    const float* __restrict__ memory, const int* __restrict__ msl,
    const float* __restrict__ prev, const float* __restrict__ cum,
    const float* __restrict__ pq_part, const float* __restrict__ v_g,
    const unsigned short* __restrict__ wt_g,
    float* __restrict__ score_g, float* __restrict__ pm_g,
    float* __restrict__ pl_g, float* __restrict__ pctx_g)
{
  const int bid = blockIdx.x;
  const int b = bid >> 2;
  const int par = bid & 3;
  const int len = msl[b];
  const int ncv = (len + 31) >> 5;               // 16..32
  const int nk = (ncv - par + 3) >> 2;           // >= 4
  const int tid = threadIdx.x;
  const int wid = tid >> 6;
  const int lane = tid & 63;

  __shared__ __align__(16) float Fst[2][16 * ND];          // 64 KB f32 staging
  __shared__ __align__(16) unsigned short sv[CT * NDA];    // 36 KB bf16
  __shared__ float pq_s[NA];
  __shared__ float v_s[NA];
  __shared__ float score2[8][CT];

  const int llo = lane & 15, lhi = lane >> 4;
  const int c = wid * 16 + llo;                  // this lane's output column

  // ---- B into registers: 18 k-frags for column c (72 VGPR, read once) ----
  short8 Bq[18];
#pragma unroll
  for (int kf = 0; kf < 18; ++kf)
    Bq[kf] = *(const short8*)(wt_g + (size_t)c * NDA + kf * 32 + lhi * 8);

  if (tid < NA) {
    const float* pp = pq_part + (size_t)b * 4 * NA + tid;
    pq_s[tid] = pp[0] + pp[NA] + pp[2 * NA] + pp[3 * NA];
    v_s[tid] = v_g[tid];
  }

  // ---- DMA issue: half h of chunk at t0 -> Fst[h]; 4 x 1KB per wave ----
#define DMA_HALF(h_, t0_) { \
  const float* base_ = memory + ((size_t)(b * NT + (t0_) + (h_) * 16)) * ND; \
  _Pragma("unroll") \
  for (int k_ = 0; k_ < 4; ++k_) \
    dma16(base_ + (wid * 4 + k_) * 256 + lane * 4, &Fst[h_][(wid * 4 + k_) * 256]); }

  // ---- convert the 2 rows this wave DMA'd (half h) + their im2col ----
#define CONVERT_HALF(h_, t0_) { \
  _Pragma("unroll") \
  for (int rr_ = 0; rr_ < 2; ++rr_) { \
    const int rloc_ = wid * 2 + rr_; \
    const int r_ = (h_) * 16 + rloc_; \
    const int sw_ = (r_ & 7) << 4; \
    const float* fp_ = &Fst[h_][rloc_ * ND + lane * 8]; \
    const f32x4 x0_ = *(const f32x4*)fp_; \
    const f32x4 x1_ = *(const f32x4*)(fp_ + 4); \
    u32x4 pk_; \
    pk_[0] = cvt_pk_bf16(x0_[0], x0_[1]); pk_[1] = cvt_pk_bf16(x0_[2], x0_[3]); \
    pk_[2] = cvt_pk_bf16(x1_[0], x1_[1]); pk_[3] = cvt_pk_bf16(x1_[2], x1_[3]); \
    *(u32x4*)((char*)sv + r_ * ROWB + ((lane * 16) ^ sw_)) = pk_; \
    const int tt_ = (t0_) + r_ - 15 + (lane >> 1); \
    float val_ = 0.f; \
    if (lane < 62 && tt_ >= 0 && tt_ < NT) \
      val_ = (lane & 1) ? cum[(size_t)b * NT + tt_] : prev[(size_t)b * NT + tt_]; \
    *(unsigned short*)((char*)sv + r_ * ROWB + ((1024 + lane * 2) ^ sw_)) = f2bf(val_); \
  } }

  // ---------------- prologue: DMA chunk 0 ----------------
  DMA_HALF(0, par * CT);
  DMA_HALF(1, par * CT);

  // ---------------- chunk loop ----------------
  for (int j = 0; j < nk; ++j) {
    const int ci = par + 4 * j;
    const int t0 = ci * CT;
    const int cid = b * NCHUNK + ci;
    const int nvalid = min(CT, len - t0);
    const int t0n = (par + 4 * (j + 1)) * CT;
    const bool more = (j + 1 < nk);

    // ---- consume h0 (4 h1-loads always pending behind it) ----
    asm volatile("s_waitcnt vmcnt(4)" ::: "memory");
    CONVERT_HALF(0, t0);
    if (more) DMA_HALF(0, t0n);
    // ---- consume h1 ----
    if (more) {
      asm volatile("s_waitcnt vmcnt(4)" ::: "memory");   // 4 new h0 behind it
    } else {
      asm volatile("s_waitcnt vmcnt(0)" ::: "memory");
    }
    CONVERT_HALF(1, t0);
    if (more) DMA_HALF(1, t0n);
    __syncthreads();   // bar1: sv complete; next-chunk DMA in flight

    // ---- GEMM: 32(t) x 16 cols/wave x 576(k); B from registers ----
    {
      const char* a0b = (const char*)sv + llo * ROWB;
      const char* a1b = a0b + 16 * ROWB;
      f32x4 acc0 = {0.f, 0.f, 0.f, 0.f};
      f32x4 acc1 = {0.f, 0.f, 0.f, 0.f};
#pragma unroll
      for (int kf = 0; kf < 18; ++kf) {
        const int bo = (kf * 64 + lhi * 16) ^ ((llo & 7) << 4);
        const short8 a0 = *(const short8*)(a0b + bo);
        const short8 a1 = *(const short8*)(a1b + bo);
        acc0 = __builtin_amdgcn_mfma_f32_16x16x32_bf16(a0, Bq[kf], acc0, 0, 0, 0);
        acc1 = __builtin_amdgcn_mfma_f32_16x16x32_bf16(a1, Bq[kf], acc1, 0, 0, 0);
      }
      const float vc = v_s[c];
      const float pqc = pq_s[c];
#pragma unroll
      for (int mf = 0; mf < 2; ++mf) {
        const f32x4 av = mf ? acc1 : acc0;
#pragma unroll
        for (int rg = 0; rg < 4; ++rg) {
          const int r = mf * 16 + lhi * 4 + rg;
          float e = fast_tanh(av[rg] + pqc) * vc;
          e += __shfl_xor(e, 1); e += __shfl_xor(e, 2);
          e += __shfl_xor(e, 4); e += __shfl_xor(e, 8);
          if (llo == 0) score2[wid][r] = e;
        }
      }
    }
    __syncthreads();   // bar2: score2 ready

    // ---- redundant all-wave softmax ----
    float esc;
    {
      const int t = lane & 31;
      float s = 0.f;
#pragma unroll
      for (int w = 0; w < 8; ++w) s += score2[w][t];
      if (wid == 0 && lane < CT) score_g[(size_t)b * NT + t0 + t] = s;
      float sm = (t < nvalid) ? s : -3.4e38f;
      sm = fmaxf(sm, __shfl_xor(sm, 1));  sm = fmaxf(sm, __shfl_xor(sm, 2));
      sm = fmaxf(sm, __shfl_xor(sm, 4));  sm = fmaxf(sm, __shfl_xor(sm, 8));
      sm = fmaxf(sm, __shfl_xor(sm, 16));
      esc = (t < nvalid) ? __expf(s - sm) : 0.f;
      float l = esc;
      l += __shfl_xor(l, 1);  l += __shfl_xor(l, 2);  l += __shfl_xor(l, 4);
      l += __shfl_xor(l, 8);  l += __shfl_xor(l, 16);
      if (wid == 0 && lane == 0) { pm_g[cid] = sm; pl_g[cid] = l; }
    }

    // ---- partial context from sv ----
    {
      const int sub = lane & 7;
      const int gi = lane >> 3;
      const int g = wid * 8 + gi;          // d-group, d0 = 8g
      const char* svb = (const char*)sv;
      float a8[8];
#pragma unroll
      for (int i = 0; i < 8; ++i) a8[i] = 0.f;
#pragma unroll
      for (int tp = 0; tp < 4; ++tp) {
        const int t = tp * 8 + sub;
        const float e = __shfl(esc, t);
        const short8 u = *(const short8*)(svb + t * ROWB + 16 * (g ^ sub));
#pragma unroll
        for (int i = 0; i < 8; ++i) a8[i] += e * bf2f((unsigned short)u[i]);
      }
#pragma unroll
      for (int off = 1; off < 8; off <<= 1) {
#pragma unroll
        for (int i = 0; i < 8; ++i) a8[i] += __shfl_xor(a8[i], off);
      }
      if (sub == 0) {
        float* dst = pctx_g + (size_t)cid * ND + g * 8;
        const f32x4 lo = {a8[0], a8[1], a8[2], a8[3]};
        const f32x4 hi = {a8[4], a8[5], a8[6], a8[7]};
        *(f32x4*)dst = lo;
        *(f32x4*)(dst + 4) = hi;
      }
    }
    __syncthreads();   // bar3: sv reads done; next convert may overwrite
  }
}

// ---------------------------------------------------------------------------
// Combine: merge 32 chunk partials per batch; write context, attn, new_cum.
// ---------------------------------------------------------------------------
__global__ __launch_bounds__(512) void lsa_comb(
    const int* __restrict__ msl, const float* __restrict__ score_g,
    const float* __restrict__ cum, const float* __restrict__ pm_g,
    const float* __restrict__ pl_g, const float* __restrict__ pctx_g,
    float* __restrict__ out)
{
  const int b = blockIdx.x;
  const int tid = threadIdx.x;
  const int len = msl[b];
  const int nck = (len + CT - 1) / CT;
  __shared__ float coef[NCHUNK];
  __shared__ float MLsh[2];
  if (tid < 64) {
    const int i = tid;
    const float m = (i < nck) ? pm_g[b * NCHUNK + i] : -3.4e38f;
    const float l = (i < nck) ? pl_g[b * NCHUNK + i] : 0.f;
    float M = m;
#pragma unroll
    for (int off = 1; off < 64; off <<= 1) M = fmaxf(M, __shfl_xor(M, off));
    const float c = __expf(m - M);
    float L = l * c;
#pragma unroll
    for (int off = 1; off < 64; off <<= 1) L += __shfl_xor(L, off);
    if (i < NCHUNK) coef[i] = c;
    if (i == 0) { MLsh[0] = M; MLsh[1] = L; }
  }
  __syncthreads();
  const float M = MLsh[0];
  const float Linv = 1.f / MLsh[1];
  {
    const int d = tid;
    float acc = 0.f;
    for (int i = 0; i < nck; ++i)
      acc += pctx_g[((size_t)b * NCHUNK + i) * ND + d] * coef[i];
    out[(size_t)b * ND + d] = acc * Linv;
  }
  float* attn_o = out + (size_t)NB * ND;
  float* cum_o = attn_o + (size_t)NB * NT;
#pragma unroll
  for (int it = 0; it < 2; ++it) {
    const int t = it * 512 + tid;
    float w = 0.f;
    if (t < len) w = __expf(score_g[(size_t)b * NT + t] - M) * Linv;
    attn_o[(size_t)b * NT + t] = w;
    cum_o[(size_t)b * NT + t] = w + cum[(size_t)b * NT + t];
  }
}

extern "C" void kernel_launch(void* const* d_in, const int* in_sizes, int n_in,
                              void* d_out, int out_size, void* d_ws, size_t ws_size,
                              hipStream_t stream) {
  const float* query  = (const float*)d_in[0];
  const float* prev   = (const float*)d_in[1];
  const float* cum    = (const float*)d_in[2];
  const float* memory = (const float*)d_in[3];
  const int*   msl    = (const int*)d_in[4];
  const float* wq     = (const float*)d_in[5];
  const float* wm     = (const float*)d_in[6];
  const float* ck     = (const float*)d_in[7];
  const float* wloc   = (const float*)d_in[8];
  const float* vv     = (const float*)d_in[9];
  float* out = (float*)d_out;

  float* ws = (float*)d_ws;
  float* score_g = ws;                        // 131072
  float* pm_g    = ws + 131072;               // 4096
  float* pl_g    = ws + 135168;               // 4096
  float* pctx_g  = ws + 139264;               // 2097152
  float* pq_part = ws + 2236416;              // 65536
  unsigned short* wt_g = (unsigned short*)(ws + 2301952);  // 128*576 bf16

  lsa_prep<<<584, 256, 0, stream>>>(query, wq, wm, ck, wloc, pq_part, wt_g);
  lsa_main<<<NB * 4, 512, 0, stream>>>(memory, msl, prev, cum, pq_part, vv,
                                       wt_g, score_g, pm_g, pl_g, pctx_g);
  lsa_comb<<<NB, 512, 0, stream>>>(msl, score_g, cum, pm_g, pl_g, pctx_g, out);
}

// Round 8
// 87.552 us; speedup vs baseline: 2.3723x; 1.2850x over previous
//
#include <hip/hip_runtime.h>
#include <hip/hip_bf16.h>

#define NB 128
#define NT 1024
#define ND 512
#define NDA 576   // 512 (memory) + 64 (im2col window, 62 used + 2 zero pad)
#define NQ 1024
#define NA 128
#define NF 32
#define NK 31
#define CT2 16
#define NCH2 (NT / CT2)    // 64
#define ROWB 1152          // bytes per LDS sv row (576 bf16)

typedef __attribute__((ext_vector_type(8))) short short8;
typedef __attribute__((ext_vector_type(4))) float f32x4;
typedef __attribute__((ext_vector_type(4))) unsigned int u32x4;
typedef __attribute__((ext_vector_type(2))) unsigned int u32x2;

__device__ __forceinline__ unsigned short f2bf(float f) {
  unsigned int u = __float_as_uint(f);
  u += 0x7fffu + ((u >> 16) & 1u);   // RNE; inputs are finite
  return (unsigned short)(u >> 16);
}
__device__ __forceinline__ unsigned int cvt_pk_bf16(float lo, float hi) {
  unsigned int r;
  asm("v_cvt_pk_bf16_f32 %0, %1, %2" : "=v"(r) : "v"(lo), "v"(hi));
  return r;
}
__device__ __forceinline__ float bf2f(unsigned short u) {
  return __uint_as_float((unsigned int)u << 16);
}
__device__ __forceinline__ float fast_tanh(float x) {
  const float e = __expf(2.f * x);
  return 1.f - 2.f / (e + 1.f);
}
// wt3 packed layout: per (col-tile ct = a>>4, kf = d>>5) a 1KB block,
// lane (lhi = (d>>3)&3, llo = a&15) holds 8 bf16 along k.
__device__ __forceinline__ int wt3_off(int a, int d) {
  return (((a >> 4) * 18 + (d >> 5)) << 9) + (((d >> 3) & 3) << 7) +
         ((a & 15) << 3) + (d & 7);
}

// ---------------------------------------------------------------------------
// Prep: pq partials (0..511), Wm^T -> wt3 (512..575), W2 = ck@Wloc (576..583)
// ---------------------------------------------------------------------------
__global__ __launch_bounds__(256) void lsa_prep(
    const float* __restrict__ query, const float* __restrict__ wq,
    const float* __restrict__ wm, const float* __restrict__ ck,
    const float* __restrict__ wloc,
    float* __restrict__ pq_part, unsigned short* __restrict__ wt3)
{
  const int bid = blockIdx.x;
  const int tid = threadIdx.x;
  if (bid < 512) {
    __shared__ float qs[256];
    __shared__ float red[256];
    const int b = bid >> 2;
    const int qg = bid & 3;
    qs[tid] = query[(size_t)b * NQ + qg * 256 + tid];
    __syncthreads();
    const int a = tid & 127;
    const int h = tid >> 7;
    const float* wqp = wq + (size_t)(qg * 256 + h * 128) * NA + a;
    float acc = 0.f;
#pragma unroll 8
    for (int qi = 0; qi < 128; ++qi)
      acc += qs[h * 128 + qi] * wqp[(size_t)qi * NA];
    red[tid] = acc;
    __syncthreads();
    if (h == 0) pq_part[((size_t)b * 4 + qg) * NA + a] = red[a] + red[128 + a];
  } else if (bid < 576) {
    const int blk = bid - 512;   // 0..63, 8 d-rows each
    for (int i = blk * 1024 + tid; i < blk * 1024 + 1024; i += 256) {
      const int dd = i >> 7, aa = i & 127;
      wt3[wt3_off(aa, dd)] = f2bf(wm[(size_t)dd * NA + aa]);
    }
  } else {
    // W2[w][a] = sum_f ck[k][ch][f]*wloc[f][a], w = 2k+ch; w=62,63 -> 0
    __shared__ float wl_s[NF * NA];
    __shared__ float ck_s[NK * 2 * NF];
    const int blk = bid - 576;   // 0..7
    for (int i = tid; i < NF * NA; i += 256) wl_s[i] = wloc[i];
    for (int i = tid; i < NK * 2 * NF; i += 256) ck_s[i] = ck[i];
    __syncthreads();
    const int a = tid & 127;
    const int h = tid >> 7;
#pragma unroll
    for (int wi = 0; wi < 4; ++wi) {
      const int w = blk * 8 + h * 4 + wi;
      float acc = 0.f;
      if (w < 62) {
        const int k = w >> 1, ch = w & 1;
#pragma unroll
        for (int f = 0; f < NF; ++f)
          acc += ck_s[k * 64 + ch * 32 + f] * wl_s[f * NA + a];
      }
      wt3[wt3_off(a, 512 + w)] = f2bf(acc);
    }
  }
}

// ---------------------------------------------------------------------------
// Main: one (b, 16-row chunk) per 256-thread block; 8 blocks/CU.
// stage -> GEMM (4 waves x 32 cols) -> softmax -> partial context.
// ---------------------------------------------------------------------------
__global__ __launch_bounds__(256, 8) void lsa_main(
    const float* __restrict__ memory, const int* __restrict__ msl,
    const float* __restrict__ prev, const float* __restrict__ cum,
    const float* __restrict__ pq_part, const float* __restrict__ v_g,
    const unsigned short* __restrict__ wt3,
    float* __restrict__ score_g, float* __restrict__ pm_g,
    float* __restrict__ pl_g, float* __restrict__ pctx_g)
{
  const int bid = blockIdx.x;
  const int b = bid >> 6;
  const int ci = bid & 63;
  const int t0 = ci * CT2;
  const int len = msl[b];
  if (t0 >= len) return;                 // fully-masked chunk: combine skips it
  const int nvalid = min(CT2, len - t0);
  const int tid = threadIdx.x;
  const int wid = tid >> 6;              // 0..3
  const int lane = tid & 63;

  __shared__ __align__(16) unsigned short sv[CT2 * NDA];  // 18 KB
  __shared__ float score2[4][CT2];

  // ---- stage values -> bf16 LDS (swizzled), rows t0..t0+15 ----
  {
    const int r = tid >> 4;        // 0..15
    const int j = tid & 15;
    const float* src = memory + ((size_t)b * NT + (t0 + r)) * ND;
    char* svb = (char*)sv + r * ROWB;
    const int sw = (r & 7) << 4;
#pragma unroll
    for (int it = 0; it < 4; ++it) {
      const int e0 = j * 8 + it * 128;
      const f32x4 x0 = *(const f32x4*)(src + e0);
      const f32x4 x1 = *(const f32x4*)(src + e0 + 4);
      u32x4 pk;
      pk[0] = cvt_pk_bf16(x0[0], x0[1]);
      pk[1] = cvt_pk_bf16(x0[2], x0[3]);
      pk[2] = cvt_pk_bf16(x1[0], x1[1]);
      pk[3] = cvt_pk_bf16(x1[2], x1[3]);
      *(u32x4*)(svb + ((e0 * 2) ^ sw)) = pk;
    }
  }
  // ---- im2col window into cols 512..575 ----
  {
    const int t = tid >> 4;
    const int w0 = (tid & 15) * 4;
    float xv[4];
#pragma unroll
    for (int i = 0; i < 4; ++i) {
      const int w = w0 + i;
      xv[i] = 0.f;
      if (w < 62) {
        const int t3 = t0 - 15 + (w >> 1) + t;
        if (t3 >= 0 && t3 < NT)
          xv[i] = (w & 1) ? cum[(size_t)b * NT + t3] : prev[(size_t)b * NT + t3];
      }
    }
    u32x2 pk;
    pk[0] = cvt_pk_bf16(xv[0], xv[1]);
    pk[1] = cvt_pk_bf16(xv[2], xv[3]);
    *(u32x2*)((char*)sv + t * ROWB + ((1024 + w0 * 2) ^ ((t & 7) << 4))) = pk;
  }
  __syncthreads();

  // ---- GEMM: 16(t) x 32 cols/wave x 576(k); B coalesced from L2 ----
  const int llo = lane & 15, lhi = lane >> 4;
  const int c0 = wid * 32 + llo;         // columns c0 and c0+16
  float esc;
  {
    const unsigned short* bbase = wt3 + ((size_t)wid * 36) * 512 + lane * 8;
    const char* ab = (const char*)sv + llo * ROWB;
    const int asw = (llo & 7) << 4;
    f32x4 acc0 = {0.f, 0.f, 0.f, 0.f};
    f32x4 acc1 = {0.f, 0.f, 0.f, 0.f};
#pragma unroll
    for (int kf = 0; kf < 18; ++kf) {
      const short8 b0 = *(const short8*)(bbase + kf * 512);
      const short8 b1 = *(const short8*)(bbase + kf * 512 + 9216);
      const short8 a = *(const short8*)(ab + ((kf * 64 + lhi * 16) ^ asw));
      acc0 = __builtin_amdgcn_mfma_f32_16x16x32_bf16(a, b0, acc0, 0, 0, 0);
      acc1 = __builtin_amdgcn_mfma_f32_16x16x32_bf16(a, b1, acc1, 0, 0, 0);
    }
    // pq (sum of 4 partials) + v, per-lane scalars from L2
    const float* pp = pq_part + (size_t)b * 4 * NA;
    const float pqa = pp[c0] + pp[NA + c0] + pp[2 * NA + c0] + pp[3 * NA + c0];
    const float pqb = pp[c0 + 16] + pp[NA + c0 + 16] + pp[2 * NA + c0 + 16] +
                      pp[3 * NA + c0 + 16];
    const float va = v_g[c0], vb = v_g[c0 + 16];
#pragma unroll
    for (int rg = 0; rg < 4; ++rg) {
      const int r = lhi * 4 + rg;
      float e = fast_tanh(acc0[rg] + pqa) * va + fast_tanh(acc1[rg] + pqb) * vb;
      e += __shfl_xor(e, 1); e += __shfl_xor(e, 2);
      e += __shfl_xor(e, 4); e += __shfl_xor(e, 8);
      if (llo == 0) score2[wid][r] = e;
    }
  }
  __syncthreads();

  // ---- redundant all-wave softmax over 16 rows ----
  {
    const int t = lane & 15;
    const float s = score2[0][t] + score2[1][t] + score2[2][t] + score2[3][t];
    if (wid == 0 && lane < CT2) score_g[(size_t)b * NT + t0 + t] = s;
    float sm = (t < nvalid) ? s : -3.4e38f;
    sm = fmaxf(sm, __shfl_xor(sm, 1));  sm = fmaxf(sm, __shfl_xor(sm, 2));
    sm = fmaxf(sm, __shfl_xor(sm, 4));  sm = fmaxf(sm, __shfl_xor(sm, 8));
    esc = (t < nvalid) ? __expf(s - sm) : 0.f;
    float l = esc;
    l += __shfl_xor(l, 1);  l += __shfl_xor(l, 2);
    l += __shfl_xor(l, 4);  l += __shfl_xor(l, 8);
    if (wid == 0 && lane == 0) {
      pm_g[b * NCH2 + ci] = sm;
      pl_g[b * NCH2 + ci] = l;
    }
  }

  // ---- partial context: wave covers 128 d's (16 groups of 8) ----
  {
    const int gi = lane >> 2;            // 0..15
    const int sub = lane & 3;            // t-part
    const int g = wid * 16 + gi;         // d-group, d0 = 8g
    const char* svb = (const char*)sv;
    float a8[8];
#pragma unroll
    for (int i = 0; i < 8; ++i) a8[i] = 0.f;
#pragma unroll
    for (int tp = 0; tp < 4; ++tp) {
      const int t2 = tp * 4 + sub;
      const float ee = __shfl(esc, t2);  // lane t2 holds esc for row t2
      const short8 u =
          *(const short8*)(svb + t2 * ROWB + ((g * 16) ^ ((t2 & 7) << 4)));
#pragma unroll
      for (int i = 0; i < 8; ++i) a8[i] += ee * bf2f((unsigned short)u[i]);
    }
#pragma unroll
    for (int i = 0; i < 8; ++i) {
      a8[i] += __shfl_xor(a8[i], 1);
      a8[i] += __shfl_xor(a8[i], 2);
    }
    if (sub == 0) {
      float* dst = pctx_g + ((size_t)(b * NCH2 + ci)) * ND + g * 8;
      const f32x4 lo = {a8[0], a8[1], a8[2], a8[3]};
      const f32x4 hi = {a8[4], a8[5], a8[6], a8[7]};
      *(f32x4*)dst = lo;
      *(f32x4*)(dst + 4) = hi;
    }
  }
}

// ---------------------------------------------------------------------------
// Combine: merge 64 chunk partials per batch; write context, attn, new_cum.
// ---------------------------------------------------------------------------
__global__ __launch_bounds__(512) void lsa_comb(
    const int* __restrict__ msl, const float* __restrict__ score_g,
    const float* __restrict__ cum, const float* __restrict__ pm_g,
    const float* __restrict__ pl_g, const float* __restrict__ pctx_g,
    float* __restrict__ out)
{
  const int b = blockIdx.x;
  const int tid = threadIdx.x;
  const int len = msl[b];
  const int nck = (len + CT2 - 1) / CT2;   // 32..64
  __shared__ float coef[NCH2];
  __shared__ float MLsh[2];
  if (tid < 64) {
    const int i = tid;
    const float m = (i < nck) ? pm_g[b * NCH2 + i] : -3.4e38f;
    const float l = (i < nck) ? pl_g[b * NCH2 + i] : 0.f;
    float M = m;
#pragma unroll
    for (int off = 1; off < 64; off <<= 1) M = fmaxf(M, __shfl_xor(M, off));
    const float c = __expf(m - M);   // exactly 0 for invalid chunks
    float L = l * c;
#pragma unroll
    for (int off = 1; off < 64; off <<= 1) L += __shfl_xor(L, off);
    coef[i] = c;
    if (i == 0) { MLsh[0] = M; MLsh[1] = L; }
  }
  __syncthreads();
  const float M = MLsh[0];
  const float Linv = 1.f / MLsh[1];
  {
    const int d = tid;   // 512 threads == D
    const float* pb = pctx_g + (size_t)b * NCH2 * ND + d;
    float a0 = 0.f, a1 = 0.f, a2 = 0.f, a3 = 0.f;
#pragma unroll 4
    for (int i = 0; i < 16; ++i) {
      a0 += pb[(size_t)i * ND] * coef[i];
      a1 += pb[(size_t)(i + 16) * ND] * coef[i + 16];
      a2 += pb[(size_t)(i + 32) * ND] * coef[i + 32];
      a3 += pb[(size_t)(i + 48) * ND] * coef[i + 48];
    }
    out[(size_t)b * ND + d] = (a0 + a1 + a2 + a3) * Linv;
  }
  float* attn_o = out + (size_t)NB * ND;
  float* cum_o = attn_o + (size_t)NB * NT;
#pragma unroll
  for (int it = 0; it < 2; ++it) {
    const int t = it * 512 + tid;
    float w = 0.f;
    if (t < len) w = __expf(score_g[(size_t)b * NT + t] - M) * Linv;
    attn_o[(size_t)b * NT + t] = w;
    cum_o[(size_t)b * NT + t] = w + cum[(size_t)b * NT + t];
  }
}

extern "C" void kernel_launch(void* const* d_in, const int* in_sizes, int n_in,
                              void* d_out, int out_size, void* d_ws, size_t ws_size,
                              hipStream_t stream) {
  const float* query  = (const float*)d_in[0];
  const float* prev   = (const float*)d_in[1];
  const float* cum    = (const float*)d_in[2];
  const float* memory = (const float*)d_in[3];
  const int*   msl    = (const int*)d_in[4];
  const float* wq     = (const float*)d_in[5];
  const float* wm     = (const float*)d_in[6];
  const float* ck     = (const float*)d_in[7];
  const float* wloc   = (const float*)d_in[8];
  const float* vv     = (const float*)d_in[9];
  float* out = (float*)d_out;

  // workspace layout (floats), ~18 MB
  float* ws = (float*)d_ws;
  float* score_g = ws;                        // 131072
  float* pm_g    = ws + 131072;               // 8192
  float* pl_g    = ws + 139264;               // 8192
  float* pctx_g  = ws + 147456;               // 128*64*512 = 4194304
  float* pq_part = ws + 4341760;              // 65536
  unsigned short* wt3 = (unsigned short*)(ws + 4407296);  // 73728 bf16

  lsa_prep<<<584, 256, 0, stream>>>(query, wq, wm, ck, wloc, pq_part, wt3);
  lsa_main<<<NB * NCH2, 256, 0, stream>>>(memory, msl, prev, cum, pq_part, vv,
                                          wt3, score_g, pm_g, pl_g, pctx_g);
  lsa_comb<<<NB, 512, 0, stream>>>(msl, score_g, cum, pm_g, pl_g, pctx_g, out);
}